// Round 1
// baseline (90.204 us; speedup 1.0000x reference)
//
#include <hip/hip_runtime.h>

// out[e] = dot(x[src[e]], W[0,:128]) + dot(x[dst[e]], W[0,128:]) + b[0]
// Factor through nodes: s[n] = x[n]·W_src, t[n] = x[n]·W_dst (x read ONCE),
// then per-edge out = s[src] + t[dst] + b  (4B gathers from L2-resident 200KB tables).

#define N_NODES 50000
#define N_EDGES 625000
#define IN_DIMS 128

// --- Detect whether edge_index is stored as int64 or int32 -----------------
// int64 little-endian: word pairs (lo, hi) with hi == 0 and lo < N_NODES.
// int32: "hi" words are real random indices in [0, 50000) — the chance all 64
// are zero is (1/50000)^64 ≈ 0. Reads 512 B, safe for either layout (buffer
// is >= 5 MB).
__global__ void detect_idx_kernel(const unsigned int* __restrict__ w,
                                  int* __restrict__ flag) {
    if (threadIdx.x == 0) {
        int is64 = 1;
        for (int k = 0; k < 64; ++k) {
            unsigned int lo = w[2 * k];
            unsigned int hi = w[2 * k + 1];
            if (hi != 0u || lo >= (unsigned)N_NODES) { is64 = 0; break; }
        }
        *flag = is64;
    }
}

// --- Kernel A: per-node dot products ---------------------------------------
// One wave per node; lane i handles dims {2i, 2i+1} -> each wave reads one
// full 512B row of x coalesced. W (1 KB) staged in LDS once per block.
__global__ __launch_bounds__(256) void node_dots_kernel(
        const float* __restrict__ x, const float* __restrict__ W,
        float* __restrict__ s, float* __restrict__ t) {
    __shared__ float Wsh[2 * IN_DIMS];
    const int tid = threadIdx.x;
    Wsh[tid] = W[tid];                 // blockDim == 256 == 2*IN_DIMS
    __syncthreads();

    const int wave = tid >> 6;
    const int lane = tid & 63;
    const int node = blockIdx.x * 4 + wave;   // 12500 * 4 == 50000 exactly

    const float2 xv  = ((const float2*)(x + (size_t)node * IN_DIMS))[lane];
    const float2 wsv = ((const float2*)Wsh)[lane];
    const float2 wdv = ((const float2*)(Wsh + IN_DIMS))[lane];

    float ps = xv.x * wsv.x + xv.y * wsv.y;
    float pt = xv.x * wdv.x + xv.y * wdv.y;

    // 64-lane butterfly reduction
    for (int off = 32; off > 0; off >>= 1) {
        ps += __shfl_xor(ps, off, 64);
        pt += __shfl_xor(pt, off, 64);
    }
    if (lane == 0) {
        s[node] = ps;
        t[node] = pt;
    }
}

// --- Kernel B: per-edge gather + add ---------------------------------------
__global__ __launch_bounds__(256) void edge_out_kernel(
        const void* __restrict__ idx,
        const float* __restrict__ s, const float* __restrict__ t,
        const float* __restrict__ b, const int* __restrict__ flag,
        float* __restrict__ out) {
    const int e = blockIdx.x * blockDim.x + threadIdx.x;
    if (e >= N_EDGES) return;
    int src, dst;
    if (*flag) {   // wave-uniform branch, flag cached in L1/L2
        const long long* p = (const long long*)idx;
        src = (int)p[e];
        dst = (int)p[N_EDGES + e];
    } else {
        const int* p = (const int*)idx;
        src = p[e];
        dst = p[N_EDGES + e];
    }
    out[e] = s[src] + t[dst] + b[0];
}

extern "C" void kernel_launch(void* const* d_in, const int* in_sizes, int n_in,
                              void* d_out, int out_size, void* d_ws, size_t ws_size,
                              hipStream_t stream) {
    const float* x   = (const float*)d_in[0];
    const void*  idx = d_in[1];                 // int32 or int64, detected on device
    const float* W   = (const float*)d_in[2];   // (1, 256)
    const float* b   = (const float*)d_in[3];   // (1,)
    float* out = (float*)d_out;

    // workspace layout: s[50000] | t[50000] | flag  (~400 KB)
    float* s    = (float*)d_ws;
    float* t    = s + N_NODES;
    int*   flag = (int*)(t + N_NODES);

    detect_idx_kernel<<<1, 64, 0, stream>>>((const unsigned int*)idx, flag);
    node_dots_kernel<<<N_NODES / 4, 256, 0, stream>>>(x, W, s, t);
    edge_out_kernel<<<(N_EDGES + 255) / 256, 256, 0, stream>>>(idx, s, t, b, flag, out);
}

// Round 2
// 85.598 us; speedup vs baseline: 1.0538x; 1.0538x over previous
//
#include <hip/hip_runtime.h>

// out[e] = dot(x[src[e]], W[0,:128]) + dot(x[dst[e]], W[0,128:]) + b[0]
// Factored through nodes: s[n] = x[n]·W_src, t[n] = x[n]·W_dst (x read ONCE),
// then per-edge out = s[src] + t[dst] + b (4B gathers from L2-resident 200KB
// tables). int64-vs-int32 index layout is detected PER-WAVE in the edge
// kernel (parallel 512B probe + ballot) — the R0 single-thread detect kernel
// was a ~25us serial dependent-load chain.

#define N_NODES 50000
#define N_EDGES 625000
#define IN_DIMS 128

// --- Kernel A: per-node dot products ---------------------------------------
// 2 nodes per wave: lanes 0-31 -> node 2w, lanes 32-63 -> node 2w+1.
// Each lane reads float4 (16B) -> one fully-coalesced 1KB transaction per
// wave covering two 512B rows of x. W (1KB) staged in LDS once per block.
__global__ __launch_bounds__(256) void node_dots_kernel(
        const float* __restrict__ x, const float* __restrict__ W,
        float* __restrict__ s, float* __restrict__ t) {
    __shared__ float Wsh[2 * IN_DIMS];
    const int tid = threadIdx.x;
    Wsh[tid] = W[tid];                 // blockDim == 256 == 2*IN_DIMS
    __syncthreads();

    const int wave = tid >> 6;
    const int half = (tid >> 5) & 1;   // which node within the wave
    const int sub  = tid & 31;         // lane within the 32-lane half
    const int node = blockIdx.x * 8 + wave * 2 + half;  // 6250*8 == 50000

    const float4 xv = ((const float4*)(x + (size_t)node * IN_DIMS))[sub];
    const float4 wsv = ((const float4*)Wsh)[sub];
    const float4 wdv = ((const float4*)(Wsh + IN_DIMS))[sub];

    float ps = xv.x * wsv.x + xv.y * wsv.y + xv.z * wsv.z + xv.w * wsv.w;
    float pt = xv.x * wdv.x + xv.y * wdv.y + xv.z * wdv.z + xv.w * wdv.w;

    // butterfly within each 32-lane half (xor offsets < 32 stay in-half)
    for (int off = 16; off > 0; off >>= 1) {
        ps += __shfl_xor(ps, off, 64);
        pt += __shfl_xor(pt, off, 64);
    }
    if (sub == 0) {
        s[node] = ps;
        t[node] = pt;
    }
}

// --- Kernel B: per-edge gather + add, 2 edges per thread --------------------
// Index dtype detection: int64 little-endian rows are (lo,hi) word pairs with
// hi==0 and lo<N_NODES; under int32 the probed words are random indices in
// [0,50000) so P(all 64 pairs look like int64) ~ (1/50000)^64 ~ 0. The 512B
// probe region is L1/L2-hot after the first wave; ballot makes the branch
// wave-uniform.
__global__ __launch_bounds__(256) void edge_out_kernel(
        const void* __restrict__ idx,
        const float* __restrict__ s, const float* __restrict__ t,
        const float* __restrict__ b, float* __restrict__ out) {
    const int lane = threadIdx.x & 63;
    const uint2 pr = ((const uint2*)idx)[lane];   // words 2*lane, 2*lane+1
    const int looks64 = (pr.y == 0u) && (pr.x < (unsigned)N_NODES);
    const bool is64 = (__ballot(looks64) == ~0ULL);

    const int i = blockIdx.x * blockDim.x + threadIdx.x;  // pair index
    if (i >= N_EDGES / 2) return;

    int src0, src1, dst0, dst1;
    if (is64) {
        const longlong2 a = ((const longlong2*)idx)[i];                  // row0
        const longlong2 c = ((const longlong2*)idx)[N_EDGES / 2 + i];    // row1
        src0 = (int)a.x; src1 = (int)a.y;
        dst0 = (int)c.x; dst1 = (int)c.y;
    } else {
        const int2 a = ((const int2*)idx)[i];
        const int2 c = ((const int2*)idx)[N_EDGES / 2 + i];
        src0 = a.x; src1 = a.y;
        dst0 = c.x; dst1 = c.y;
    }

    const float bb = b[0];
    float2 o;
    o.x = s[src0] + t[dst0] + bb;
    o.y = s[src1] + t[dst1] + bb;
    ((float2*)out)[i] = o;
}

extern "C" void kernel_launch(void* const* d_in, const int* in_sizes, int n_in,
                              void* d_out, int out_size, void* d_ws, size_t ws_size,
                              hipStream_t stream) {
    const float* x   = (const float*)d_in[0];
    const void*  idx = d_in[1];                 // int32 or int64, detected per-wave
    const float* W   = (const float*)d_in[2];   // (1, 256)
    const float* b   = (const float*)d_in[3];   // (1,)
    float* out = (float*)d_out;

    // workspace layout: s[50000] | t[50000]  (~400 KB)
    float* s = (float*)d_ws;
    float* t = s + N_NODES;

    node_dots_kernel<<<N_NODES / 8, 256, 0, stream>>>(x, W, s, t);
    edge_out_kernel<<<(N_EDGES / 2 + 255) / 256, 256, 0, stream>>>(idx, s, t, b, out);
}

// Round 3
// 83.315 us; speedup vs baseline: 1.0827x; 1.0274x over previous
//
#include <hip/hip_runtime.h>

// out[e] = dot(x[src[e]], W[0,:128]) + dot(x[dst[e]], W[0,128:]) + b[0]
// Factored through nodes: s[n] = x[n]·W_src, t[n] = x[n]·W_dst (x read ONCE),
// then per-edge out = s[src] + t[dst] + b (4B gathers from L2-resident 200KB
// tables). Mandatory traffic: 25.6MB x + 10MB idx + 2.5MB out ~= 38MB ~= 6us
// floor at 6.3TB/s. Harness adds ~60-70us fixed (268MB ws poison + restores).

#define N_NODES 50000
#define N_EDGES 625000
#define IN_DIMS 128

// --- Kernel A: per-node dot products ---------------------------------------
// 2 nodes per wave: lanes 0-31 -> node 2w, lanes 32-63 -> node 2w+1.
// Each lane reads float4 (16B) -> one fully-coalesced 1KB transaction per
// wave covering two 512B rows of x. W (1KB) is read per-lane directly from
// global (L1/L2-hot across all blocks) — no LDS staging, no __syncthreads.
__global__ __launch_bounds__(256) void node_dots_kernel(
        const float* __restrict__ x, const float* __restrict__ W,
        float* __restrict__ s, float* __restrict__ t) {
    const int tid  = threadIdx.x;
    const int wave = tid >> 6;
    const int half = (tid >> 5) & 1;   // which node within the wave
    const int sub  = tid & 31;         // lane within the 32-lane half
    const int node = blockIdx.x * 8 + wave * 2 + half;  // 6250*8 == 50000

    const float4 xv  = ((const float4*)(x + (size_t)node * IN_DIMS))[sub];
    const float4 wsv = ((const float4*)W)[sub];
    const float4 wdv = ((const float4*)(W + IN_DIMS))[sub];

    float ps = xv.x * wsv.x + xv.y * wsv.y + xv.z * wsv.z + xv.w * wsv.w;
    float pt = xv.x * wdv.x + xv.y * wdv.y + xv.z * wdv.z + xv.w * wdv.w;

    // butterfly within each 32-lane half (xor offsets < 32 stay in-half)
    for (int off = 16; off > 0; off >>= 1) {
        ps += __shfl_xor(ps, off, 64);
        pt += __shfl_xor(pt, off, 64);
    }
    if (sub == 0) {
        s[node] = ps;
        t[node] = pt;
    }
}

// --- Kernel B: per-edge gather + add, 4 edges per thread --------------------
// Index dtype detection: int64 little-endian rows are (lo,hi) word pairs with
// hi==0 and lo<N_NODES; under int32 the probed words are random indices in
// [0,50000) so P(all 64 pairs look like int64) ~ (1/50000)^64 ~ 0. The 512B
// probe region is L1/L2-hot after the first wave; ballot makes the branch
// wave-uniform. Row offsets: 625000*8B and 625000*4B are both 16B-aligned,
// so longlong2/int4 vector loads are legal at quad boundaries.
__global__ __launch_bounds__(256) void edge_out_kernel(
        const void* __restrict__ idx,
        const float* __restrict__ s, const float* __restrict__ t,
        const float* __restrict__ b, float* __restrict__ out) {
    const int lane = threadIdx.x & 63;
    const uint2 pr = ((const uint2*)idx)[lane];   // words 2*lane, 2*lane+1
    const int looks64 = (pr.y == 0u) && (pr.x < (unsigned)N_NODES);
    const bool is64 = (__ballot(looks64) == ~0ULL);

    const int q = blockIdx.x * blockDim.x + threadIdx.x;  // quad index
    if (q >= N_EDGES / 4) return;

    int src[4], dst[4];
    if (is64) {
        const longlong2* p = (const longlong2*)idx;
        const longlong2 a0 = p[2 * q];                      // src edges 4q..4q+1
        const longlong2 a1 = p[2 * q + 1];                  // src edges 4q+2..4q+3
        const longlong2 c0 = p[N_EDGES / 2 + 2 * q];        // dst row
        const longlong2 c1 = p[N_EDGES / 2 + 2 * q + 1];
        src[0] = (int)a0.x; src[1] = (int)a0.y; src[2] = (int)a1.x; src[3] = (int)a1.y;
        dst[0] = (int)c0.x; dst[1] = (int)c0.y; dst[2] = (int)c1.x; dst[3] = (int)c1.y;
    } else {
        const int4* p = (const int4*)idx;
        const int4 a = p[q];
        const int4 c = p[N_EDGES / 4 + q];
        src[0] = a.x; src[1] = a.y; src[2] = a.z; src[3] = a.w;
        dst[0] = c.x; dst[1] = c.y; dst[2] = c.z; dst[3] = c.w;
    }

    const float bb = b[0];
    float4 o;
    o.x = s[src[0]] + t[dst[0]] + bb;
    o.y = s[src[1]] + t[dst[1]] + bb;
    o.z = s[src[2]] + t[dst[2]] + bb;
    o.w = s[src[3]] + t[dst[3]] + bb;
    ((float4*)out)[q] = o;
}

extern "C" void kernel_launch(void* const* d_in, const int* in_sizes, int n_in,
                              void* d_out, int out_size, void* d_ws, size_t ws_size,
                              hipStream_t stream) {
    const float* x   = (const float*)d_in[0];
    const void*  idx = d_in[1];                 // int32 or int64, detected per-wave
    const float* W   = (const float*)d_in[2];   // (1, 256)
    const float* b   = (const float*)d_in[3];   // (1,)
    float* out = (float*)d_out;

    // workspace layout: s[50000] | t[50000]  (~400 KB)
    float* s = (float*)d_ws;
    float* t = s + N_NODES;

    node_dots_kernel<<<N_NODES / 8, 256, 0, stream>>>(x, W, s, t);
    edge_out_kernel<<<(N_EDGES / 4 + 255) / 256, 256, 0, stream>>>(idx, s, t, b, out);
}